// Round 6
// baseline (330.234 us; speedup 1.0000x reference)
//
#include <hip/hip_runtime.h>
#include <cstddef>

static constexpr int CB = 64;    // batch
static constexpr int CN = 512;   // nodes
static constexpr int CD = 256;   // node model dim
static constexpr int CE = 128;   // edge model dim
static constexpr int CIT = 20;   // sinkhorn iterations

typedef _Float16 half_t;
typedef __attribute__((ext_vector_type(8))) _Float16 v8h;
typedef __attribute__((ext_vector_type(4))) _Float16 v4h;
typedef __attribute__((ext_vector_type(4))) float v4f;

// ---------------------------------------------------------------------------
// k0: block 0 = mask layout detect; block 1 = zero barrier counters;
// blocks 2..9 = W_a -> fp16 B-fragments (w_aff folded); blocks 10..17 = W_b;
// blocks >= 18 = clear the dataflow slot region to -1.0f (sentinel).
// flag: 0=int32, 1=uint8(bool), 2=float32, 3=int64
// ---------------------------------------------------------------------------
__global__ __launch_bounds__(512) void k0_init(
    const void* __restrict__ mask, int* __restrict__ bar, int* __restrict__ flag,
    const float* __restrict__ W_a, const float* __restrict__ W_b,
    const float* __restrict__ w_aff,
    half_t* __restrict__ WaF, half_t* __restrict__ WbF,
    float4* __restrict__ clearp, int nclear4) {
  const int tid = threadIdx.x;
  const int blk = blockIdx.x;
  if (blk == 1) {
#pragma unroll
    for (int k = 0; k < 4; ++k) bar[tid * 4 + k] = 0;
    return;
  }
  if (blk >= 18) {
    const int idx = (blk - 18) * 512 + tid;
    if (idx < nclear4)
      clearp[idx] = make_float4(-1.0f, -1.0f, -1.0f, -1.0f);
    return;
  }
  if (blk >= 2) {
    const bool is_a = (blk < 10);
    const float* W = is_a ? W_a : W_b;
    half_t* WF = is_a ? WaF : WbF;
    const int e = (blk - (is_a ? 2 : 10)) * 512 + tid;   // 0..4095
    const int fB = e >> 6, lane = e & 63;
    const int nn = fB >> 3, kf = fB & 7;
    const int col = nn * 16 + (lane & 15);
    const int q = lane >> 4;
    const float scale = is_a ? w_aff[col] : 1.0f;
    v8h hv;
#pragma unroll
    for (int j = 0; j < 8; ++j) {
      const int k = kf * 32 + q * 8 + j;
      hv[j] = (half_t)(W[(size_t)k * CE + col] * scale);
    }
    *(v8h*)&WF[(size_t)e * 8] = hv;
    return;
  }
  // blk == 0: mask dtype detection over first 32768 bytes
  __shared__ int cnt[5];
  if (tid < 5) cnt[tid] = 0;
  __syncthreads();
  const unsigned char* p = (const unsigned char*)mask;
  int l0 = 0, l1 = 0, l2 = 0, l3 = 0, l4 = 0;
  const int base = tid * 64;
  for (int k = 0; k < 64; ++k) {
    const int off = base + k;
    if (p[off]) {
      const int m4 = off & 3;
      if (m4 == 1) l1++;
      else if (m4 == 2) l2++;
      else if (m4 == 3) l3++;
      else if ((off & 7) == 4) l4++;
      else l0++;
    }
  }
  if (l0) atomicAdd(&cnt[0], 1);
  if (l1) atomicAdd(&cnt[1], 1);
  if (l2) atomicAdd(&cnt[2], 1);
  if (l3) atomicAdd(&cnt[3], 1);
  if (l4) atomicAdd(&cnt[4], 1);
  __syncthreads();
  if (tid == 0) {
    int f;
    if (cnt[1]) f = 1;
    else if (cnt[2] || cnt[3]) f = 2;
    else if (cnt[4]) f = 0;
    else if (cnt[0]) f = 3;
    else f = 1;
    *flag = f;
  }
}

// ---------------------------------------------------------------------------
// prep_mfma: out[row,col] fp16 row-major, M=32768, N=128, K=256.
// 512 blocks x 256 thr, 64 rows/block. Coalesced staging: wave owns a row per
// iteration, lane ln covers cols 4ln..4ln+3 (contiguous 1 KB/wave). LDS tile
// row-major fp16, stride 264 halfs (16B-aligned rows; staging writes 2-way
// bank-aliased = free). MFMA reads A-fragments from LDS (8 reads/wave).
// MODE 0: x = out_emb + pos, W = WaF (w_aff folded).
// MODE 1: x = mask ? pad : in_emb, W = WbF.
// ---------------------------------------------------------------------------
template <int MODE>
__global__ __launch_bounds__(256) void prep_mfma(
    const float* __restrict__ X, const float* __restrict__ extra,
    const void* __restrict__ maskp, const int* __restrict__ flagp,
    const half_t* __restrict__ Wfrag, half_t* __restrict__ out) {
  __shared__ half_t Xs[64][264];   // 33.8 KB
  const int tid = threadIdx.x;
  const int wv = tid >> 6, ln = tid & 63;
  const int row0 = blockIdx.x * 64;
  const int flag = (MODE == 1) ? *flagp : 0;

  // ---- stage 64 rows x 256 cols, fully coalesced ----
#pragma unroll 4
  for (int it = 0; it < 16; ++it) {
    const int r = it * 4 + wv;
    const int row = row0 + r;
    const int c = ln * 4;
    float4 x4;
    if (MODE == 0) {
      x4 = *(const float4*)&X[(size_t)row * CD + c];
      const int i = row & (CN - 1);
      const float4 p4 = *(const float4*)&extra[(size_t)i * CD + c];
      x4.x += p4.x; x4.y += p4.y; x4.z += p4.z; x4.w += p4.w;
    } else {
      bool m;
      if (flag == 1)      m = ((const unsigned char*)maskp)[row] != 0;
      else if (flag == 2) m = ((const float*)maskp)[row] != 0.0f;
      else if (flag == 3) m = ((const long long*)maskp)[row] != 0;
      else                m = ((const int*)maskp)[row] != 0;
      if (m) x4 = *(const float4*)&extra[c];
      else   x4 = *(const float4*)&X[(size_t)row * CD + c];
    }
    v4h hv;
    hv[0] = (half_t)x4.x; hv[1] = (half_t)x4.y;
    hv[2] = (half_t)x4.z; hv[3] = (half_t)x4.w;
    *(v4h*)&Xs[r][c] = hv;
  }
  __syncthreads();

  // ---- MFMA: wave wv owns m-tile wv (rows wv*16 .. wv*16+15) ----
  const int q = ln >> 4, l = ln & 15;
  v8h af[8];
#pragma unroll
  for (int kf = 0; kf < 8; ++kf)
    af[kf] = *(v8h*)&Xs[wv * 16 + l][kf * 32 + q * 8];
  v4f acc[8] = {};
#pragma unroll
  for (int nn = 0; nn < 8; ++nn) {
    v8h bf[8];
#pragma unroll
    for (int kf = 0; kf < 8; ++kf)
      bf[kf] = *(const v8h*)&Wfrag[(size_t)((nn * 8 + kf) * 64 + ln) * 8];
#pragma unroll
    for (int kf = 0; kf < 8; ++kf)
      acc[nn] = __builtin_amdgcn_mfma_f32_16x16x32_f16(af[kf], bf[kf], acc[nn], 0, 0, 0);
  }
#pragma unroll
  for (int nn = 0; nn < 8; ++nn)
#pragma unroll
    for (int g = 0; g < 4; ++g) {
      const int row = row0 + wv * 16 + q * 4 + g;
      out[(size_t)row * CE + nn * 16 + l] = (half_t)acc[nn][g];
    }
}

// ---------------------------------------------------------------------------
// fused_reg: block = (batch b, 128-row slab), 512 thr = 8 waves, grid 256 =
// 1 block/CU. E slab in fp32 registers (128 VGPR/thread), MFMA C-layout:
//   ef[ct][g] <-> E[row = wv*16 + q*4 + g][col = ct*16 + l].
// exp(aff + b_aff - ln16): 2^-4 scale cancels in both normalizations.
// PROTO 0: barrier-free dataflow sync. Every exchange round has a write-once
//   slot pre-cleared to -1; partials are strictly positive, so consumers poll
//   the 6 remote words until > 0. No counters, no fences (relaxed agent
//   atomics; R5-validated visibility model).
// PROTO 1: R5's proven counter-barrier fallback (if ws too small).
// ---------------------------------------------------------------------------
template <int PROTO>
__global__ __launch_bounds__(512) void fused_reg(
    const half_t* __restrict__ A_h, const half_t* __restrict__ B_h,
    const float* __restrict__ baff, float* __restrict__ P,
    float* __restrict__ partInit, float* __restrict__ partIter,
    float* __restrict__ part1, int* __restrict__ bar) {
  __shared__ float comb[8][2][512];      // 32 KB
  __shared__ float2 w12[512];            // {0.5*v*csinv, v}
  __shared__ float csinv_l[512];
  __shared__ float rinv_l[128];

  const int tid = threadIdx.x;
  const int wv = tid >> 6, ln = tid & 63;
  const int q = ln >> 4, l = ln & 15;
  const int b = blockIdx.x & 63;
  const int slab = blockIdx.x >> 6;
  const int i0 = slab * 128;
  const float bbs = *baff - 2.7725887f;   // fold 2^-4 scale into exp

  int rs3[3];   // the 3 remote slabs
  {
    int k = 0;
#pragma unroll
    for (int sl = 0; sl < 4; ++sl)
      if (sl != slab) rs3[k++] = sl;
  }

  // ---- GEMM: 16 rows x 512 cols per wave, K=128, fp16 MFMA + fused init ----
  v8h af[4];
  {
    const half_t* Arow = &A_h[((size_t)b * CN + i0 + wv * 16 + l) * CE];
#pragma unroll
    for (int ki = 0; ki < 4; ++ki)
      af[ki] = *(const v8h*)&Arow[ki * 32 + q * 8];
  }
  float ef[32][4];                       // E slab, fp32, 128 VGPRs
  float d[4] = {0.0f, 0.0f, 0.0f, 0.0f};
  const half_t* Bbase = &B_h[(size_t)b * CN * CE];
#pragma unroll
  for (int ct = 0; ct < 32; ++ct) {
    v8h bf[4];
    const half_t* Brow = &Bbase[(size_t)(ct * 16 + l) * CE];
#pragma unroll
    for (int ki = 0; ki < 4; ++ki)
      bf[ki] = *(const v8h*)&Brow[ki * 32 + q * 8];
    v4f acc = {};
#pragma unroll
    for (int ki = 0; ki < 4; ++ki)
      acc = __builtin_amdgcn_mfma_f32_16x16x32_f16(af[ki], bf[ki], acc, 0, 0, 0);
    float colsum = 0.0f;
#pragma unroll
    for (int g = 0; g < 4; ++g) {
      const float e = __expf(acc[g] + bbs);
      ef[ct][g] = e;
      d[g] += e;
      colsum += e;
    }
    colsum += __shfl_xor(colsum, 16);
    colsum += __shfl_xor(colsum, 32);
    if (ln < 16) comb[wv][0][ct * 16 + ln] = colsum;
  }
#pragma unroll
  for (int g = 0; g < 4; ++g) {
#pragma unroll
    for (int m = 1; m < 16; m <<= 1) d[g] += __shfl_xor(d[g], m);
  }
  if (l == 0) {
#pragma unroll
    for (int g = 0; g < 4; ++g) rinv_l[wv * 16 + q * 4 + g] = 1.0f / d[g];
  }
  __syncthreads();

#define PIDX1(slot, bb, sl, var, col) \
  ((((((size_t)(slot)*64 + (bb)) * 4 + (sl)) * 2 + (var)) * 512) + (col))

  int gen = 0;
  // ---- init exchange: column sums -> csinv; w init (v = 1) ----
  {
    float S = 0.0f;
#pragma unroll
    for (int w = 0; w < 8; ++w) S += comb[w][0][tid];
    float T = S;
    if (PROTO == 0) {
      __hip_atomic_store(&partInit[(((size_t)b * 4 + slab) * 512) + tid], S,
                         __ATOMIC_RELAXED, __HIP_MEMORY_SCOPE_AGENT);
      float v0, v1, v2;
      float* pb = &partInit[(size_t)b * 4 * 512];
      while (true) {
        v0 = __hip_atomic_load(&pb[rs3[0] * 512 + tid], __ATOMIC_RELAXED, __HIP_MEMORY_SCOPE_AGENT);
        v1 = __hip_atomic_load(&pb[rs3[1] * 512 + tid], __ATOMIC_RELAXED, __HIP_MEMORY_SCOPE_AGENT);
        v2 = __hip_atomic_load(&pb[rs3[2] * 512 + tid], __ATOMIC_RELAXED, __HIP_MEMORY_SCOPE_AGENT);
        if (v0 > 0.0f && v1 > 0.0f && v2 > 0.0f) break;
        __builtin_amdgcn_s_sleep(1);
      }
      T += v0 + v1 + v2;
    } else {
      __hip_atomic_store(&part1[PIDX1(0, b, slab, 0, tid)], S,
                         __ATOMIC_RELAXED, __HIP_MEMORY_SCOPE_AGENT);
      ++gen;
      __syncthreads();
      if (tid == 0) {
        __hip_atomic_fetch_add(&bar[b * 32], 1, __ATOMIC_RELAXED, __HIP_MEMORY_SCOPE_AGENT);
        while (__hip_atomic_load(&bar[b * 32], __ATOMIC_RELAXED, __HIP_MEMORY_SCOPE_AGENT) < 4 * gen)
          __builtin_amdgcn_s_sleep(2);
      }
      __syncthreads();
#pragma unroll
      for (int sl = 0; sl < 4; ++sl) {
        if (sl == slab) continue;
        T += __hip_atomic_load(&part1[PIDX1(0, b, sl, 0, tid)],
                               __ATOMIC_RELAXED, __HIP_MEMORY_SCOPE_AGENT);
      }
    }
    const float ci = 1.0f / T;
    csinv_l[tid] = ci;
    w12[tid] = make_float2(0.5f * ci, 1.0f);
  }
  float rv[4];
#pragma unroll
  for (int g = 0; g < 4; ++g) rv[g] = rinv_l[wv * 16 + q * 4 + g];

  // ---- 20 sinkhorn iterations ----
  float u_[4], uri[4];
  for (int t = 0; t < CIT; ++t) {
    __syncthreads();   // w12 ready
    float p1[4] = {0, 0, 0, 0}, p2[4] = {0, 0, 0, 0};
#pragma unroll
    for (int ct = 0; ct < 32; ++ct) {
      const float2 w = w12[ct * 16 + l];
#pragma unroll
      for (int g = 0; g < 4; ++g) {
        const float e = ef[ct][g];
        p1[g] = fmaf(e, w.x, p1[g]);
        p2[g] = fmaf(e, w.y, p2[g]);
      }
    }
#pragma unroll
    for (int g = 0; g < 4; ++g) {
#pragma unroll
      for (int m = 1; m < 16; m <<= 1) {
        p1[g] += __shfl_xor(p1[g], m);
        p2[g] += __shfl_xor(p2[g], m);
      }
      u_[g] = 1.0f / (p1[g] + 0.5f * rv[g] * p2[g]);
      uri[g] = u_[g] * rv[g];
    }
#pragma unroll
    for (int ct = 0; ct < 32; ++ct) {
      float s1 = 0.0f, s2 = 0.0f;
#pragma unroll
      for (int g = 0; g < 4; ++g) {
        const float e = ef[ct][g];
        s1 = fmaf(e, u_[g], s1);
        s2 = fmaf(e, uri[g], s2);
      }
      s1 += __shfl_xor(s1, 16); s1 += __shfl_xor(s1, 32);
      s2 += __shfl_xor(s2, 16); s2 += __shfl_xor(s2, 32);
      if (ln < 16) {
        comb[wv][0][ct * 16 + ln] = s1;
        comb[wv][1][ct * 16 + ln] = s2;
      }
    }
    __syncthreads();
    float S1 = 0.0f, S2 = 0.0f;
#pragma unroll
    for (int w = 0; w < 8; ++w) {
      S1 += comb[w][0][tid];
      S2 += comb[w][1][tid];
    }
    float T1 = S1, T2 = S2;
    if (PROTO == 0) {
      // write-once slot for round t; poll remote words until positive
      float* pr = &partIter[(((size_t)t * 64 + b) * 4) * 1024];
      __hip_atomic_store(&pr[slab * 1024 + tid], S1,
                         __ATOMIC_RELAXED, __HIP_MEMORY_SCOPE_AGENT);
      __hip_atomic_store(&pr[slab * 1024 + 512 + tid], S2,
                         __ATOMIC_RELAXED, __HIP_MEMORY_SCOPE_AGENT);
      float v0, v1, v2, v3, v4, v5;
      while (true) {
        v0 = __hip_atomic_load(&pr[rs3[0] * 1024 + tid],       __ATOMIC_RELAXED, __HIP_MEMORY_SCOPE_AGENT);
        v1 = __hip_atomic_load(&pr[rs3[0] * 1024 + 512 + tid], __ATOMIC_RELAXED, __HIP_MEMORY_SCOPE_AGENT);
        v2 = __hip_atomic_load(&pr[rs3[1] * 1024 + tid],       __ATOMIC_RELAXED, __HIP_MEMORY_SCOPE_AGENT);
        v3 = __hip_atomic_load(&pr[rs3[1] * 1024 + 512 + tid], __ATOMIC_RELAXED, __HIP_MEMORY_SCOPE_AGENT);
        v4 = __hip_atomic_load(&pr[rs3[2] * 1024 + tid],       __ATOMIC_RELAXED, __HIP_MEMORY_SCOPE_AGENT);
        v5 = __hip_atomic_load(&pr[rs3[2] * 1024 + 512 + tid], __ATOMIC_RELAXED, __HIP_MEMORY_SCOPE_AGENT);
        if (v0 > 0.0f && v1 > 0.0f && v2 > 0.0f &&
            v3 > 0.0f && v4 > 0.0f && v5 > 0.0f) break;
        __builtin_amdgcn_s_sleep(1);
      }
      T1 += v0 + v2 + v4;
      T2 += v1 + v3 + v5;
    } else {
      const int slot = gen & 1;
      __hip_atomic_store(&part1[PIDX1(slot, b, slab, 0, tid)], S1,
                         __ATOMIC_RELAXED, __HIP_MEMORY_SCOPE_AGENT);
      __hip_atomic_store(&part1[PIDX1(slot, b, slab, 1, tid)], S2,
                         __ATOMIC_RELAXED, __HIP_MEMORY_SCOPE_AGENT);
      ++gen;
      __syncthreads();
      if (tid == 0) {
        __hip_atomic_fetch_add(&bar[b * 32], 1, __ATOMIC_RELAXED, __HIP_MEMORY_SCOPE_AGENT);
        while (__hip_atomic_load(&bar[b * 32], __ATOMIC_RELAXED, __HIP_MEMORY_SCOPE_AGENT) < 4 * gen)
          __builtin_amdgcn_s_sleep(2);
      }
      __syncthreads();
#pragma unroll
      for (int sl = 0; sl < 4; ++sl) {
        if (sl == slab) continue;
        T1 += __hip_atomic_load(&part1[PIDX1(slot, b, sl, 0, tid)],
                                __ATOMIC_RELAXED, __HIP_MEMORY_SCOPE_AGENT);
        T2 += __hip_atomic_load(&part1[PIDX1(slot, b, sl, 1, tid)],
                                __ATOMIC_RELAXED, __HIP_MEMORY_SCOPE_AGENT);
      }
    }
    const float ci = csinv_l[tid];
    const float vv = 1.0f / (0.5f * fmaf(ci, T1, T2));
    w12[tid] = make_float2(0.5f * vv * ci, vv);
  }

  // ---- finalize: P = E * u_i * v_j * (0.5*csinv_j + 0.5*rinv_i) ----
  __syncthreads();
  float* Pb = &P[((size_t)b * CN + i0 + wv * 16 + q * 4) * CN];
#pragma unroll
  for (int ct = 0; ct < 32; ++ct) {
    const float2 w = w12[ct * 16 + l];
    const float c1 = w.x;
    const float c2 = 0.5f * w.y;
#pragma unroll
    for (int g = 0; g < 4; ++g) {
      const float e = ef[ct][g];
      Pb[(size_t)g * CN + ct * 16 + l] = e * fmaf(u_[g], c1, uri[g] * c2);
    }
  }
#undef PIDX1
}

// ---------------------------------------------------------------------------
extern "C" void kernel_launch(void* const* d_in, const int* in_sizes, int n_in,
                              void* d_out, int out_size, void* d_ws, size_t ws_size,
                              hipStream_t stream) {
  const float* in_emb  = (const float*)d_in[0];
  const void*  mask    = d_in[1];
  const float* out_emb = (const float*)d_in[2];
  const float* pad     = (const float*)d_in[3];
  const float* pos     = (const float*)d_in[4];
  const float* W_a     = (const float*)d_in[5];
  const float* W_b     = (const float*)d_in[6];
  const float* w_aff   = (const float*)d_in[7];
  const float* b_aff   = (const float*)d_in[8];
  float* P = (float*)d_out;

  char* ws = (char*)d_ws;
  const size_t MB = 1024 * 1024;
  half_t* A_h  = (half_t*)ws;                              // 8 MB
  half_t* Bm_h = (half_t*)(ws + 8 * MB);                   // 8 MB
  int*    flag = (int*)(ws + 16 * MB);                     // 4 B
  int*    bar  = (int*)(ws + 16 * MB + 4096);              // 8 KB
  half_t* WaF  = (half_t*)(ws + 16 * MB + 16384);          // 64 KB
  half_t* WbF  = (half_t*)(ws + 16 * MB + 16384 + 65536);  // 64 KB
  float* partInit = (float*)(ws + 16 * MB + 256 * 1024);   // 512 KB (proto0)
  float* partIter = (float*)(ws + 16 * MB + 768 * 1024);   // 20 MB  (proto0)
  float* part1    = partInit;                              // 2 MB   (proto1)

  const size_t need0 = 16 * MB + 768 * 1024 + 20 * MB;
  const int proto = (ws_size >= need0) ? 0 : 1;
  // dataflow slots: 20.5 MB contiguous starting at partInit
  const int nclear4 = (512 * 1024 + 20 * 1024 * 1024) / 16;   // 1,343,488 float4
  const int nclrblk = (nclear4 + 511) / 512;                  // 2624

  k0_init<<<dim3(proto == 0 ? 18 + nclrblk : 18), dim3(512), 0, stream>>>(
      mask, bar, flag, W_a, W_b, w_aff, WaF, WbF, (float4*)partInit, nclear4);
  prep_mfma<0><<<dim3(CB * CN / 64), dim3(256), 0, stream>>>(
      out_emb, pos, nullptr, flag, WaF, A_h);
  prep_mfma<1><<<dim3(CB * CN / 64), dim3(256), 0, stream>>>(
      in_emb, pad, mask, flag, WbF, Bm_h);
  if (proto == 0) {
    fused_reg<0><<<dim3(256), dim3(512), 0, stream>>>(
        A_h, Bm_h, b_aff, P, partInit, partIter, part1, bar);
  } else {
    fused_reg<1><<<dim3(256), dim3(512), 0, stream>>>(
        A_h, Bm_h, b_aff, P, partInit, partIter, part1, bar);
  }
}

// Round 7
// 326.274 us; speedup vs baseline: 1.0121x; 1.0121x over previous
//
#include <hip/hip_runtime.h>
#include <cstddef>

static constexpr int CB = 64;    // batch
static constexpr int CN = 512;   // nodes
static constexpr int CD = 256;   // node model dim
static constexpr int CE = 128;   // edge model dim
static constexpr int CIT = 20;   // sinkhorn iterations

typedef _Float16 half_t;
typedef __attribute__((ext_vector_type(8))) _Float16 v8h;
typedef __attribute__((ext_vector_type(4))) _Float16 v4h;
typedef __attribute__((ext_vector_type(4))) float v4f;

// ---------------------------------------------------------------------------
// k0: block 0 = mask layout detect; block 1 = zero barrier counters;
// blocks 2..9 = W_a -> fp16 B-fragments (w_aff folded); blocks 10..17 = W_b;
// blocks >= 18 = clear the dataflow slot region to -1.0f (sentinel).
// flag: 0=int32, 1=uint8(bool), 2=float32, 3=int64
// ---------------------------------------------------------------------------
__global__ __launch_bounds__(512) void k0_init(
    const void* __restrict__ mask, int* __restrict__ bar, int* __restrict__ flag,
    const float* __restrict__ W_a, const float* __restrict__ W_b,
    const float* __restrict__ w_aff,
    half_t* __restrict__ WaF, half_t* __restrict__ WbF,
    float4* __restrict__ clearp, int nclear4) {
  const int tid = threadIdx.x;
  const int blk = blockIdx.x;
  if (blk == 1) {
#pragma unroll
    for (int k = 0; k < 4; ++k) bar[tid * 4 + k] = 0;
    return;
  }
  if (blk >= 18) {
    const int idx = (blk - 18) * 512 + tid;
    if (idx < nclear4)
      clearp[idx] = make_float4(-1.0f, -1.0f, -1.0f, -1.0f);
    return;
  }
  if (blk >= 2) {
    const bool is_a = (blk < 10);
    const float* W = is_a ? W_a : W_b;
    half_t* WF = is_a ? WaF : WbF;
    const int e = (blk - (is_a ? 2 : 10)) * 512 + tid;   // 0..4095
    const int fB = e >> 6, lane = e & 63;
    const int nn = fB >> 3, kf = fB & 7;
    const int col = nn * 16 + (lane & 15);
    const int q = lane >> 4;
    const float scale = is_a ? w_aff[col] : 1.0f;
    v8h hv;
#pragma unroll
    for (int j = 0; j < 8; ++j) {
      const int k = kf * 32 + q * 8 + j;
      hv[j] = (half_t)(W[(size_t)k * CE + col] * scale);
    }
    *(v8h*)&WF[(size_t)e * 8] = hv;
    return;
  }
  // blk == 0: mask dtype detection over first 32768 bytes
  __shared__ int cnt[5];
  if (tid < 5) cnt[tid] = 0;
  __syncthreads();
  const unsigned char* p = (const unsigned char*)mask;
  int l0 = 0, l1 = 0, l2 = 0, l3 = 0, l4 = 0;
  const int base = tid * 64;
  for (int k = 0; k < 64; ++k) {
    const int off = base + k;
    if (p[off]) {
      const int m4 = off & 3;
      if (m4 == 1) l1++;
      else if (m4 == 2) l2++;
      else if (m4 == 3) l3++;
      else if ((off & 7) == 4) l4++;
      else l0++;
    }
  }
  if (l0) atomicAdd(&cnt[0], 1);
  if (l1) atomicAdd(&cnt[1], 1);
  if (l2) atomicAdd(&cnt[2], 1);
  if (l3) atomicAdd(&cnt[3], 1);
  if (l4) atomicAdd(&cnt[4], 1);
  __syncthreads();
  if (tid == 0) {
    int f;
    if (cnt[1]) f = 1;
    else if (cnt[2] || cnt[3]) f = 2;
    else if (cnt[4]) f = 0;
    else if (cnt[0]) f = 3;
    else f = 1;
    *flag = f;
  }
}

// ---------------------------------------------------------------------------
// prep_both: ONE dispatch for both prep GEMMs. Blocks 0..511 = A-path
// (x = out_emb + pos, W = WaF w/ w_aff folded); 512..1023 = B-path
// (x = mask ? pad : in_emb, W = WbF). out fp16 row-major [32768,128], K=256.
// Coalesced staging: wave owns a row/iter, lane ln covers cols 4ln..4ln+3.
// ---------------------------------------------------------------------------
__global__ __launch_bounds__(256) void prep_both(
    const float* __restrict__ out_emb, const float* __restrict__ pos,
    const float* __restrict__ in_emb, const float* __restrict__ pad,
    const void* __restrict__ maskp, const int* __restrict__ flagp,
    const half_t* __restrict__ WaF, const half_t* __restrict__ WbF,
    half_t* __restrict__ A_h, half_t* __restrict__ Bm_h) {
  __shared__ half_t Xs[64][264];   // 33.8 KB
  const int tid = threadIdx.x;
  const int wv = tid >> 6, ln = tid & 63;
  const bool isA = blockIdx.x < 512;
  const int row0 = (isA ? blockIdx.x : blockIdx.x - 512) * 64;
  const float* X = isA ? out_emb : in_emb;
  const float* extra = isA ? pos : pad;
  const half_t* Wfrag = isA ? WaF : WbF;
  half_t* out = isA ? A_h : Bm_h;
  const int flag = isA ? 0 : *flagp;

  // ---- stage 64 rows x 256 cols, fully coalesced ----
#pragma unroll 4
  for (int it = 0; it < 16; ++it) {
    const int r = it * 4 + wv;
    const int row = row0 + r;
    const int c = ln * 4;
    float4 x4;
    if (isA) {
      x4 = *(const float4*)&X[(size_t)row * CD + c];
      const int i = row & (CN - 1);
      const float4 p4 = *(const float4*)&extra[(size_t)i * CD + c];
      x4.x += p4.x; x4.y += p4.y; x4.z += p4.z; x4.w += p4.w;
    } else {
      bool m;
      if (flag == 1)      m = ((const unsigned char*)maskp)[row] != 0;
      else if (flag == 2) m = ((const float*)maskp)[row] != 0.0f;
      else if (flag == 3) m = ((const long long*)maskp)[row] != 0;
      else                m = ((const int*)maskp)[row] != 0;
      if (m) x4 = *(const float4*)&extra[c];
      else   x4 = *(const float4*)&X[(size_t)row * CD + c];
    }
    v4h hv;
    hv[0] = (half_t)x4.x; hv[1] = (half_t)x4.y;
    hv[2] = (half_t)x4.z; hv[3] = (half_t)x4.w;
    *(v4h*)&Xs[r][c] = hv;
  }
  __syncthreads();

  // ---- MFMA: wave wv owns m-tile wv (rows wv*16 .. wv*16+15) ----
  const int q = ln >> 4, l = ln & 15;
  v8h af[8];
#pragma unroll
  for (int kf = 0; kf < 8; ++kf)
    af[kf] = *(v8h*)&Xs[wv * 16 + l][kf * 32 + q * 8];
  v4f acc[8] = {};
#pragma unroll
  for (int nn = 0; nn < 8; ++nn) {
    v8h bf[8];
#pragma unroll
    for (int kf = 0; kf < 8; ++kf)
      bf[kf] = *(const v8h*)&Wfrag[(size_t)((nn * 8 + kf) * 64 + ln) * 8];
#pragma unroll
    for (int kf = 0; kf < 8; ++kf)
      acc[nn] = __builtin_amdgcn_mfma_f32_16x16x32_f16(af[kf], bf[kf], acc[nn], 0, 0, 0);
  }
#pragma unroll
  for (int nn = 0; nn < 8; ++nn)
#pragma unroll
    for (int g = 0; g < 4; ++g) {
      const int row = row0 + wv * 16 + q * 4 + g;
      out[(size_t)row * CE + nn * 16 + l] = (half_t)acc[nn][g];
    }
}

// ---------------------------------------------------------------------------
// fused_reg: block = (batch b, 128-row slab), 512 thr = 8 waves, grid 256 =
// 1 block/CU. __launch_bounds__(512, 2): 8 waves/block = 2 waves/EU, raising
// the VGPR cap to 256 so ef[32][4] (128 VGPRs) stays IN REGISTERS (R6's
// (512) default capped at ~100 and spilled the E slab to scratch).
// E slab fp32, MFMA C-layout: ef[ct][g] <-> E[row=wv*16+q*4+g][col=ct*16+l].
// exp(aff + b_aff - ln16): 2^-4 scale cancels in both normalizations.
// Sync: barrier-free dataflow (write-once slots pre-cleared to -1; partials
// strictly positive; relaxed agent atomics only — validated R5/R6).
// ---------------------------------------------------------------------------
__global__ __launch_bounds__(512, 2) void fused_reg(
    const half_t* __restrict__ A_h, const half_t* __restrict__ B_h,
    const float* __restrict__ baff, float* __restrict__ P,
    float* __restrict__ partInit, float* __restrict__ partIter) {
  __shared__ float comb[8][2][512];      // 32 KB
  __shared__ float2 w12[512];            // {0.5*v*csinv, v}
  __shared__ float csinv_l[512];
  __shared__ float rinv_l[128];

  const int tid = threadIdx.x;
  const int wv = tid >> 6, ln = tid & 63;
  const int q = ln >> 4, l = ln & 15;
  const int b = blockIdx.x & 63;
  const int slab = blockIdx.x >> 6;
  const int i0 = slab * 128;
  const float bbs = *baff - 2.7725887f;   // fold 2^-4 scale into exp

  int rs3[3];   // the 3 remote slabs
  {
    int k = 0;
#pragma unroll
    for (int sl = 0; sl < 4; ++sl)
      if (sl != slab) rs3[k++] = sl;
  }

  // ---- GEMM: 16 rows x 512 cols per wave, K=128, fp16 MFMA + fused init ----
  v8h af[4];
  {
    const half_t* Arow = &A_h[((size_t)b * CN + i0 + wv * 16 + l) * CE];
#pragma unroll
    for (int ki = 0; ki < 4; ++ki)
      af[ki] = *(const v8h*)&Arow[ki * 32 + q * 8];
  }
  float ef[32][4];                       // E slab, fp32, 128 VGPRs
  float d[4] = {0.0f, 0.0f, 0.0f, 0.0f};
  const half_t* Bbase = &B_h[(size_t)b * CN * CE];
#pragma unroll
  for (int ct = 0; ct < 32; ++ct) {
    v8h bf[4];
    const half_t* Brow = &Bbase[(size_t)(ct * 16 + l) * CE];
#pragma unroll
    for (int ki = 0; ki < 4; ++ki)
      bf[ki] = *(const v8h*)&Brow[ki * 32 + q * 8];
    v4f acc = {};
#pragma unroll
    for (int ki = 0; ki < 4; ++ki)
      acc = __builtin_amdgcn_mfma_f32_16x16x32_f16(af[ki], bf[ki], acc, 0, 0, 0);
    float colsum = 0.0f;
#pragma unroll
    for (int g = 0; g < 4; ++g) {
      const float e = __expf(acc[g] + bbs);
      ef[ct][g] = e;
      d[g] += e;
      colsum += e;
    }
    colsum += __shfl_xor(colsum, 16);
    colsum += __shfl_xor(colsum, 32);
    if (ln < 16) comb[wv][0][ct * 16 + ln] = colsum;
  }
#pragma unroll
  for (int g = 0; g < 4; ++g) {
#pragma unroll
    for (int m = 1; m < 16; m <<= 1) d[g] += __shfl_xor(d[g], m);
  }
  if (l == 0) {
#pragma unroll
    for (int g = 0; g < 4; ++g) rinv_l[wv * 16 + q * 4 + g] = 1.0f / d[g];
  }
  __syncthreads();

  // ---- init exchange: column sums -> csinv; w init (v = 1) ----
  {
    float S = 0.0f;
#pragma unroll
    for (int w = 0; w < 8; ++w) S += comb[w][0][tid];
    float T = S;
    __hip_atomic_store(&partInit[(((size_t)b * 4 + slab) * 512) + tid], S,
                       __ATOMIC_RELAXED, __HIP_MEMORY_SCOPE_AGENT);
    float v0, v1, v2;
    float* pb = &partInit[(size_t)b * 4 * 512];
    while (true) {
      v0 = __hip_atomic_load(&pb[rs3[0] * 512 + tid], __ATOMIC_RELAXED, __HIP_MEMORY_SCOPE_AGENT);
      v1 = __hip_atomic_load(&pb[rs3[1] * 512 + tid], __ATOMIC_RELAXED, __HIP_MEMORY_SCOPE_AGENT);
      v2 = __hip_atomic_load(&pb[rs3[2] * 512 + tid], __ATOMIC_RELAXED, __HIP_MEMORY_SCOPE_AGENT);
      if (v0 > 0.0f && v1 > 0.0f && v2 > 0.0f) break;
      __builtin_amdgcn_s_sleep(1);
    }
    T += v0 + v1 + v2;
    const float ci = 1.0f / T;
    csinv_l[tid] = ci;
    w12[tid] = make_float2(0.5f * ci, 1.0f);
  }
  float rv[4];
#pragma unroll
  for (int g = 0; g < 4; ++g) rv[g] = rinv_l[wv * 16 + q * 4 + g];

  // ---- 20 sinkhorn iterations ----
  float u_[4], uri[4];
  for (int t = 0; t < CIT; ++t) {
    __syncthreads();   // w12 ready
    float p1[4] = {0, 0, 0, 0}, p2[4] = {0, 0, 0, 0};
#pragma unroll
    for (int ct = 0; ct < 32; ++ct) {
      const float2 w = w12[ct * 16 + l];
#pragma unroll
      for (int g = 0; g < 4; ++g) {
        const float e = ef[ct][g];
        p1[g] = fmaf(e, w.x, p1[g]);
        p2[g] = fmaf(e, w.y, p2[g]);
      }
    }
#pragma unroll
    for (int g = 0; g < 4; ++g) {
#pragma unroll
      for (int m = 1; m < 16; m <<= 1) {
        p1[g] += __shfl_xor(p1[g], m);
        p2[g] += __shfl_xor(p2[g], m);
      }
      u_[g] = 1.0f / (p1[g] + 0.5f * rv[g] * p2[g]);
      uri[g] = u_[g] * rv[g];
    }
#pragma unroll
    for (int ct = 0; ct < 32; ++ct) {
      float s1 = 0.0f, s2 = 0.0f;
#pragma unroll
      for (int g = 0; g < 4; ++g) {
        const float e = ef[ct][g];
        s1 = fmaf(e, u_[g], s1);
        s2 = fmaf(e, uri[g], s2);
      }
      s1 += __shfl_xor(s1, 16); s1 += __shfl_xor(s1, 32);
      s2 += __shfl_xor(s2, 16); s2 += __shfl_xor(s2, 32);
      if (ln < 16) {
        comb[wv][0][ct * 16 + ln] = s1;
        comb[wv][1][ct * 16 + ln] = s2;
      }
    }
    __syncthreads();
    float S1 = 0.0f, S2 = 0.0f;
#pragma unroll
    for (int w = 0; w < 8; ++w) {
      S1 += comb[w][0][tid];
      S2 += comb[w][1][tid];
    }
    float T1 = S1, T2 = S2;
    // write-once slot for round t; poll remote words until positive
    float* pr = &partIter[(((size_t)t * 64 + b) * 4) * 1024];
    __hip_atomic_store(&pr[slab * 1024 + tid], S1,
                       __ATOMIC_RELAXED, __HIP_MEMORY_SCOPE_AGENT);
    __hip_atomic_store(&pr[slab * 1024 + 512 + tid], S2,
                       __ATOMIC_RELAXED, __HIP_MEMORY_SCOPE_AGENT);
    float v0, v1, v2, v3, v4, v5;
    while (true) {
      v0 = __hip_atomic_load(&pr[rs3[0] * 1024 + tid],       __ATOMIC_RELAXED, __HIP_MEMORY_SCOPE_AGENT);
      v1 = __hip_atomic_load(&pr[rs3[0] * 1024 + 512 + tid], __ATOMIC_RELAXED, __HIP_MEMORY_SCOPE_AGENT);
      v2 = __hip_atomic_load(&pr[rs3[1] * 1024 + tid],       __ATOMIC_RELAXED, __HIP_MEMORY_SCOPE_AGENT);
      v3 = __hip_atomic_load(&pr[rs3[1] * 1024 + 512 + tid], __ATOMIC_RELAXED, __HIP_MEMORY_SCOPE_AGENT);
      v4 = __hip_atomic_load(&pr[rs3[2] * 1024 + tid],       __ATOMIC_RELAXED, __HIP_MEMORY_SCOPE_AGENT);
      v5 = __hip_atomic_load(&pr[rs3[2] * 1024 + 512 + tid], __ATOMIC_RELAXED, __HIP_MEMORY_SCOPE_AGENT);
      if (v0 > 0.0f && v1 > 0.0f && v2 > 0.0f &&
          v3 > 0.0f && v4 > 0.0f && v5 > 0.0f) break;
      __builtin_amdgcn_s_sleep(1);
    }
    T1 += v0 + v2 + v4;
    T2 += v1 + v3 + v5;
    const float ci = csinv_l[tid];
    const float vv = 1.0f / (0.5f * fmaf(ci, T1, T2));
    w12[tid] = make_float2(0.5f * vv * ci, vv);
  }

  // ---- finalize: P = E * u_i * v_j * (0.5*csinv_j + 0.5*rinv_i) ----
  __syncthreads();
  float* Pb = &P[((size_t)b * CN + i0 + wv * 16 + q * 4) * CN];
#pragma unroll
  for (int ct = 0; ct < 32; ++ct) {
    const float2 w = w12[ct * 16 + l];
    const float c1 = w.x;
    const float c2 = 0.5f * w.y;
#pragma unroll
    for (int g = 0; g < 4; ++g) {
      const float e = ef[ct][g];
      Pb[(size_t)g * CN + ct * 16 + l] = e * fmaf(u_[g], c1, uri[g] * c2);
    }
  }
}

// ---------------------------------------------------------------------------
extern "C" void kernel_launch(void* const* d_in, const int* in_sizes, int n_in,
                              void* d_out, int out_size, void* d_ws, size_t ws_size,
                              hipStream_t stream) {
  const float* in_emb  = (const float*)d_in[0];
  const void*  mask    = d_in[1];
  const float* out_emb = (const float*)d_in[2];
  const float* pad     = (const float*)d_in[3];
  const float* pos     = (const float*)d_in[4];
  const float* W_a     = (const float*)d_in[5];
  const float* W_b     = (const float*)d_in[6];
  const float* w_aff   = (const float*)d_in[7];
  const float* b_aff   = (const float*)d_in[8];
  float* P = (float*)d_out;

  char* ws = (char*)d_ws;
  const size_t MB = 1024 * 1024;
  half_t* A_h  = (half_t*)ws;                              // 8 MB
  half_t* Bm_h = (half_t*)(ws + 8 * MB);                   // 8 MB
  int*    flag = (int*)(ws + 16 * MB);                     // 4 B
  int*    bar  = (int*)(ws + 16 * MB + 4096);              // 8 KB
  half_t* WaF  = (half_t*)(ws + 16 * MB + 16384);          // 64 KB
  half_t* WbF  = (half_t*)(ws + 16 * MB + 16384 + 65536);  // 64 KB
  float* partInit = (float*)(ws + 16 * MB + 256 * 1024);   // 512 KB
  float* partIter = (float*)(ws + 16 * MB + 768 * 1024);   // 20 MB

  // dataflow slots: 20.5 MB contiguous starting at partInit
  const int nclear4 = (512 * 1024 + 20 * 1024 * 1024) / 16;   // 1,343,488 float4
  const int nclrblk = (nclear4 + 511) / 512;                  // 2624

  k0_init<<<dim3(18 + nclrblk), dim3(512), 0, stream>>>(
      mask, bar, flag, W_a, W_b, w_aff, WaF, WbF, (float4*)partInit, nclear4);
  prep_both<<<dim3(1024), dim3(256), 0, stream>>>(
      out_emb, pos, in_emb, pad, mask, flag, WaF, WbF, A_h, Bm_h);
  fused_reg<<<dim3(256), dim3(512), 0, stream>>>(
      A_h, Bm_h, b_aff, P, partInit, partIter);
}

// Round 8
// 309.647 us; speedup vs baseline: 1.0665x; 1.0537x over previous
//
#include <hip/hip_runtime.h>
#include <cstddef>

static constexpr int CB = 64;    // batch
static constexpr int CN = 512;   // nodes
static constexpr int CD = 256;   // node model dim
static constexpr int CE = 128;   // edge model dim
static constexpr int CIT = 20;   // sinkhorn iterations

typedef _Float16 half_t;
typedef __attribute__((ext_vector_type(8))) _Float16 v8h;
typedef __attribute__((ext_vector_type(4))) _Float16 v4h;
typedef __attribute__((ext_vector_type(4))) float v4f;

// ---------------------------------------------------------------------------
// k0: block 0 = mask layout detect; block 1 = idle; blocks 2..9 = W_a -> fp16
// B-fragments (w_aff folded); 10..17 = W_b; blocks >= 18 clear the dataflow
// slot region to -1.0f. flag: 0=int32, 1=uint8(bool), 2=float32, 3=int64
// ---------------------------------------------------------------------------
__global__ __launch_bounds__(512) void k0_init(
    const void* __restrict__ mask, int* __restrict__ flag,
    const float* __restrict__ W_a, const float* __restrict__ W_b,
    const float* __restrict__ w_aff,
    half_t* __restrict__ WaF, half_t* __restrict__ WbF,
    float4* __restrict__ clearp, int nclear4) {
  const int tid = threadIdx.x;
  const int blk = blockIdx.x;
  if (blk == 1) return;
  if (blk >= 18) {
    const int idx = (blk - 18) * 512 + tid;
    if (idx < nclear4)
      clearp[idx] = make_float4(-1.0f, -1.0f, -1.0f, -1.0f);
    return;
  }
  if (blk >= 2) {
    const bool is_a = (blk < 10);
    const float* W = is_a ? W_a : W_b;
    half_t* WF = is_a ? WaF : WbF;
    const int e = (blk - (is_a ? 2 : 10)) * 512 + tid;   // 0..4095
    const int fB = e >> 6, lane = e & 63;
    const int nn = fB >> 3, kf = fB & 7;
    const int col = nn * 16 + (lane & 15);
    const int q = lane >> 4;
    const float scale = is_a ? w_aff[col] : 1.0f;
    v8h hv;
#pragma unroll
    for (int j = 0; j < 8; ++j) {
      const int k = kf * 32 + q * 8 + j;
      hv[j] = (half_t)(W[(size_t)k * CE + col] * scale);
    }
    *(v8h*)&WF[(size_t)e * 8] = hv;
    return;
  }
  // blk == 0: mask dtype detection over first 32768 bytes
  __shared__ int cnt[5];
  if (tid < 5) cnt[tid] = 0;
  __syncthreads();
  const unsigned char* p = (const unsigned char*)mask;
  int l0 = 0, l1 = 0, l2 = 0, l3 = 0, l4 = 0;
  const int base = tid * 64;
  for (int k = 0; k < 64; ++k) {
    const int off = base + k;
    if (p[off]) {
      const int m4 = off & 3;
      if (m4 == 1) l1++;
      else if (m4 == 2) l2++;
      else if (m4 == 3) l3++;
      else if ((off & 7) == 4) l4++;
      else l0++;
    }
  }
  if (l0) atomicAdd(&cnt[0], 1);
  if (l1) atomicAdd(&cnt[1], 1);
  if (l2) atomicAdd(&cnt[2], 1);
  if (l3) atomicAdd(&cnt[3], 1);
  if (l4) atomicAdd(&cnt[4], 1);
  __syncthreads();
  if (tid == 0) {
    int f;
    if (cnt[1]) f = 1;
    else if (cnt[2] || cnt[3]) f = 2;
    else if (cnt[4]) f = 0;
    else if (cnt[0]) f = 3;
    else f = 1;
    *flag = f;
  }
}

// ---------------------------------------------------------------------------
// prep_both (validated R7): ONE dispatch for both prep GEMMs. Blocks 0..511 =
// A-path (x = out_emb + pos, W = WaF w/ w_aff folded); 512..1023 = B-path
// (x = mask ? pad : in_emb, W = WbF). out fp16 row-major [32768,128], K=256.
// ---------------------------------------------------------------------------
__global__ __launch_bounds__(256) void prep_both(
    const float* __restrict__ out_emb, const float* __restrict__ pos,
    const float* __restrict__ in_emb, const float* __restrict__ pad,
    const void* __restrict__ maskp, const int* __restrict__ flagp,
    const half_t* __restrict__ WaF, const half_t* __restrict__ WbF,
    half_t* __restrict__ A_h, half_t* __restrict__ Bm_h) {
  __shared__ half_t Xs[64][264];   // 33.8 KB
  const int tid = threadIdx.x;
  const int wv = tid >> 6, ln = tid & 63;
  const bool isA = blockIdx.x < 512;
  const int row0 = (isA ? blockIdx.x : blockIdx.x - 512) * 64;
  const float* X = isA ? out_emb : in_emb;
  const float* extra = isA ? pos : pad;
  const half_t* Wfrag = isA ? WaF : WbF;
  half_t* out = isA ? A_h : Bm_h;
  const int flag = isA ? 0 : *flagp;

#pragma unroll 4
  for (int it = 0; it < 16; ++it) {
    const int r = it * 4 + wv;
    const int row = row0 + r;
    const int c = ln * 4;
    float4 x4;
    if (isA) {
      x4 = *(const float4*)&X[(size_t)row * CD + c];
      const int i = row & (CN - 1);
      const float4 p4 = *(const float4*)&extra[(size_t)i * CD + c];
      x4.x += p4.x; x4.y += p4.y; x4.z += p4.z; x4.w += p4.w;
    } else {
      bool m;
      if (flag == 1)      m = ((const unsigned char*)maskp)[row] != 0;
      else if (flag == 2) m = ((const float*)maskp)[row] != 0.0f;
      else if (flag == 3) m = ((const long long*)maskp)[row] != 0;
      else                m = ((const int*)maskp)[row] != 0;
      if (m) x4 = *(const float4*)&extra[c];
      else   x4 = *(const float4*)&X[(size_t)row * CD + c];
    }
    v4h hv;
    hv[0] = (half_t)x4.x; hv[1] = (half_t)x4.y;
    hv[2] = (half_t)x4.z; hv[3] = (half_t)x4.w;
    *(v4h*)&Xs[r][c] = hv;
  }
  __syncthreads();

  const int q = ln >> 4, l = ln & 15;
  v8h af[8];
#pragma unroll
  for (int kf = 0; kf < 8; ++kf)
    af[kf] = *(v8h*)&Xs[wv * 16 + l][kf * 32 + q * 8];
  v4f acc[8] = {};
#pragma unroll
  for (int nn = 0; nn < 8; ++nn) {
    v8h bf[8];
#pragma unroll
    for (int kf = 0; kf < 8; ++kf)
      bf[kf] = *(const v8h*)&Wfrag[(size_t)((nn * 8 + kf) * 64 + ln) * 8];
#pragma unroll
    for (int kf = 0; kf < 8; ++kf)
      acc[nn] = __builtin_amdgcn_mfma_f32_16x16x32_f16(af[kf], bf[kf], acc[nn], 0, 0, 0);
  }
#pragma unroll
  for (int nn = 0; nn < 8; ++nn)
#pragma unroll
    for (int g = 0; g < 4; ++g) {
      const int row = row0 + wv * 16 + q * 4 + g;
      out[(size_t)row * CE + nn * 16 + l] = (half_t)acc[nn][g];
    }
}

// ---------------------------------------------------------------------------
// fused_reg: block = (batch b, 128-row slab), 512 thr = 8 waves, grid 256 =
// 1 block/CU, __launch_bounds__(512,2) (256-VGPR budget; ef lives in the
// unified VGPR/AGPR file). E slab fp32, MFMA C-layout:
//   ef[ct][g] <-> E[row=wv*16+q*4+g][col=ct*16+l].
// exp(aff + b_aff - ln16): 2^-4 scale cancels in both normalizations.
// Sync: barrier-free dataflow slots (pre-cleared -1, strictly-positive
// payloads, relaxed agent atomics — validated R5-R7). NEW vs R7:
//  * publish ONE pre-combined word/col: Q = 0.5*(ci*S1 + S2); poll 3 words.
//  * pass2 q-reduce via 3-swizzle cross-send trick + half-wave LDS write.
//  * comb packed as float2 [8][512][2] -> 8 b64 reads in cross-wave reduce.
// ---------------------------------------------------------------------------
__global__ __launch_bounds__(512, 2) void fused_reg(
    const half_t* __restrict__ A_h, const half_t* __restrict__ B_h,
    const float* __restrict__ baff, float* __restrict__ P,
    float* __restrict__ partInit, float* __restrict__ partIter) {
  __shared__ float comb2[8][512][2];     // 32 KB, [wave][col][s1|s2]
  __shared__ float2 w12[512];            // {0.5*v*csinv, v}
  __shared__ float csinv_l[512];
  __shared__ float rinv_l[128];

  const int tid = threadIdx.x;
  const int wv = tid >> 6, ln = tid & 63;
  const int q = ln >> 4, l = ln & 15;
  const int b = blockIdx.x & 63;
  const int slab = blockIdx.x >> 6;
  const int i0 = slab * 128;
  const float bbs = *baff - 2.7725887f;   // fold 2^-4 scale into exp

  int rs3[3];   // the 3 remote slabs
  {
    int k = 0;
#pragma unroll
    for (int sl = 0; sl < 4; ++sl)
      if (sl != slab) rs3[k++] = sl;
  }

  // ---- GEMM: 16 rows x 512 cols per wave, K=128, fp16 MFMA + fused init ----
  v8h af[4];
  {
    const half_t* Arow = &A_h[((size_t)b * CN + i0 + wv * 16 + l) * CE];
#pragma unroll
    for (int ki = 0; ki < 4; ++ki)
      af[ki] = *(const v8h*)&Arow[ki * 32 + q * 8];
  }
  float ef[32][4];                       // E slab, fp32 (unified VGPR/AGPR)
  float d[4] = {0.0f, 0.0f, 0.0f, 0.0f};
  const half_t* Bbase = &B_h[(size_t)b * CN * CE];
#pragma unroll
  for (int ct = 0; ct < 32; ++ct) {
    v8h bf[4];
    const half_t* Brow = &Bbase[(size_t)(ct * 16 + l) * CE];
#pragma unroll
    for (int ki = 0; ki < 4; ++ki)
      bf[ki] = *(const v8h*)&Brow[ki * 32 + q * 8];
    v4f acc = {};
#pragma unroll
    for (int ki = 0; ki < 4; ++ki)
      acc = __builtin_amdgcn_mfma_f32_16x16x32_f16(af[ki], bf[ki], acc, 0, 0, 0);
    float colsum = 0.0f;
#pragma unroll
    for (int g = 0; g < 4; ++g) {
      const float e = __expf(acc[g] + bbs);
      ef[ct][g] = e;
      d[g] += e;
      colsum += e;
    }
    colsum += __shfl_xor(colsum, 16);
    colsum += __shfl_xor(colsum, 32);
    if (ln < 16) comb2[wv][ct * 16 + ln][0] = colsum;
  }
#pragma unroll
  for (int g = 0; g < 4; ++g) {
#pragma unroll
    for (int m = 1; m < 16; m <<= 1) d[g] += __shfl_xor(d[g], m);
  }
  if (l == 0) {
#pragma unroll
    for (int g = 0; g < 4; ++g) rinv_l[wv * 16 + q * 4 + g] = 1.0f / d[g];
  }
  __syncthreads();

  // ---- init exchange: column sums -> csinv; w init (v = 1) ----
  {
    float S = 0.0f;
#pragma unroll
    for (int w = 0; w < 8; ++w) S += comb2[w][tid][0];
    float T = S;
    __hip_atomic_store(&partInit[(((size_t)b * 4 + slab) * 512) + tid], S,
                       __ATOMIC_RELAXED, __HIP_MEMORY_SCOPE_AGENT);
    float v0, v1, v2;
    float* pb = &partInit[(size_t)b * 4 * 512];
    while (true) {
      v0 = __hip_atomic_load(&pb[rs3[0] * 512 + tid], __ATOMIC_RELAXED, __HIP_MEMORY_SCOPE_AGENT);
      v1 = __hip_atomic_load(&pb[rs3[1] * 512 + tid], __ATOMIC_RELAXED, __HIP_MEMORY_SCOPE_AGENT);
      v2 = __hip_atomic_load(&pb[rs3[2] * 512 + tid], __ATOMIC_RELAXED, __HIP_MEMORY_SCOPE_AGENT);
      if (v0 > 0.0f && v1 > 0.0f && v2 > 0.0f) break;
      __builtin_amdgcn_s_sleep(1);
    }
    T += v0 + v1 + v2;
    const float ci = 1.0f / T;
    csinv_l[tid] = ci;
    w12[tid] = make_float2(0.5f * ci, 1.0f);
  }
  float rv[4];
#pragma unroll
  for (int g = 0; g < 4; ++g) rv[g] = rinv_l[wv * 16 + q * 4 + g];

  // ---- 20 sinkhorn iterations ----
  float u_[4], uri[4];
  for (int t = 0; t < CIT; ++t) {
    __syncthreads();   // w12 ready
    // pass 1: row dots -> u
    float p1[4] = {0, 0, 0, 0}, p2[4] = {0, 0, 0, 0};
#pragma unroll
    for (int ct = 0; ct < 32; ++ct) {
      const float2 w = w12[ct * 16 + l];
#pragma unroll
      for (int g = 0; g < 4; ++g) {
        const float e = ef[ct][g];
        p1[g] = fmaf(e, w.x, p1[g]);
        p2[g] = fmaf(e, w.y, p2[g]);
      }
    }
#pragma unroll
    for (int g = 0; g < 4; ++g) {
#pragma unroll
      for (int m = 1; m < 16; m <<= 1) {
        p1[g] += __shfl_xor(p1[g], m);
        p2[g] += __shfl_xor(p2[g], m);
      }
      u_[g] = 1.0f / (p1[g] + 0.5f * rv[g] * p2[g]);
      uri[g] = u_[g] * rv[g];
    }
    // pass 2: column partials; 3-swizzle q-reduce (low lanes keep s1, high s2)
#pragma unroll
    for (int ct = 0; ct < 32; ++ct) {
      float s1 = 0.0f, s2 = 0.0f;
#pragma unroll
      for (int g = 0; g < 4; ++g) {
        const float e = ef[ct][g];
        s1 = fmaf(e, u_[g], s1);
        s2 = fmaf(e, uri[g], s2);
      }
      s1 += __shfl_xor(s1, 16);
      s2 += __shfl_xor(s2, 16);
      const float sel = (ln >= 32) ? s1 : s2;
      const float recv = __shfl_xor(sel, 32);
      const float z = ((ln < 32) ? s1 : s2) + recv;
      if ((ln & 16) == 0) comb2[wv][ct * 16 + (ln & 15)][ln >> 5] = z;
    }
    __syncthreads();
    // cross-wave reduce + pre-combined publish: Q = 0.5*(ci*S1 + S2)
    float S1 = 0.0f, S2 = 0.0f;
#pragma unroll
    for (int w = 0; w < 8; ++w) {
      const float2 c2 = *(const float2*)&comb2[w][tid][0];
      S1 += c2.x;
      S2 += c2.y;
    }
    const float ci = csinv_l[tid];
    const float Q = 0.5f * fmaf(ci, S1, S2);
    float* pr = &partIter[(((size_t)t * 64 + b) * 4) * 512];
    __hip_atomic_store(&pr[slab * 512 + tid], Q,
                       __ATOMIC_RELAXED, __HIP_MEMORY_SCOPE_AGENT);
    float v0, v1, v2;
    while (true) {
      v0 = __hip_atomic_load(&pr[rs3[0] * 512 + tid], __ATOMIC_RELAXED, __HIP_MEMORY_SCOPE_AGENT);
      v1 = __hip_atomic_load(&pr[rs3[1] * 512 + tid], __ATOMIC_RELAXED, __HIP_MEMORY_SCOPE_AGENT);
      v2 = __hip_atomic_load(&pr[rs3[2] * 512 + tid], __ATOMIC_RELAXED, __HIP_MEMORY_SCOPE_AGENT);
      if (v0 > 0.0f && v1 > 0.0f && v2 > 0.0f) break;
      __builtin_amdgcn_s_sleep(1);
    }
    const float vv = 1.0f / (Q + v0 + v1 + v2);
    w12[tid] = make_float2(0.5f * vv * ci, vv);
  }

  // ---- finalize: P = E * u_i * v_j * (0.5*csinv_j + 0.5*rinv_i) ----
  __syncthreads();
  float* Pb = &P[((size_t)b * CN + i0 + wv * 16 + q * 4) * CN];
#pragma unroll
  for (int ct = 0; ct < 32; ++ct) {
    const float2 w = w12[ct * 16 + l];
    const float c1 = w.x;
    const float c2 = 0.5f * w.y;
#pragma unroll
    for (int g = 0; g < 4; ++g) {
      const float e = ef[ct][g];
      Pb[(size_t)g * CN + ct * 16 + l] = e * fmaf(u_[g], c1, uri[g] * c2);
    }
  }
}

// ---------------------------------------------------------------------------
extern "C" void kernel_launch(void* const* d_in, const int* in_sizes, int n_in,
                              void* d_out, int out_size, void* d_ws, size_t ws_size,
                              hipStream_t stream) {
  const float* in_emb  = (const float*)d_in[0];
  const void*  mask    = d_in[1];
  const float* out_emb = (const float*)d_in[2];
  const float* pad     = (const float*)d_in[3];
  const float* pos     = (const float*)d_in[4];
  const float* W_a     = (const float*)d_in[5];
  const float* W_b     = (const float*)d_in[6];
  const float* w_aff   = (const float*)d_in[7];
  const float* b_aff   = (const float*)d_in[8];
  float* P = (float*)d_out;

  char* ws = (char*)d_ws;
  const size_t MB = 1024 * 1024;
  half_t* A_h  = (half_t*)ws;                              // 8 MB
  half_t* Bm_h = (half_t*)(ws + 8 * MB);                   // 8 MB
  int*    flag = (int*)(ws + 16 * MB);                     // 4 B
  half_t* WaF  = (half_t*)(ws + 16 * MB + 16384);          // 64 KB
  half_t* WbF  = (half_t*)(ws + 16 * MB + 16384 + 65536);  // 64 KB
  float* partInit = (float*)(ws + 16 * MB + 256 * 1024);   // 512 KB
  float* partIter = (float*)(ws + 16 * MB + 768 * 1024);   // 10 MB

  // dataflow slots: 10.5 MB contiguous starting at partInit
  const int nclear4 = (512 * 1024 + 10 * 1024 * 1024) / 16;   // 688,128 float4
  const int nclrblk = (nclear4 + 511) / 512;                  // 1344

  k0_init<<<dim3(18 + nclrblk), dim3(512), 0, stream>>>(
      mask, flag, W_a, W_b, w_aff, WaF, WbF, (float4*)partInit, nclear4);
  prep_both<<<dim3(1024), dim3(256), 0, stream>>>(
      out_emb, pos, in_emb, pad, mask, flag, WaF, WbF, A_h, Bm_h);
  fused_reg<<<dim3(256), dim3(512), 0, stream>>>(
      A_h, Bm_h, b_aff, P, partInit, partIter);
}

// Round 9
// 305.165 us; speedup vs baseline: 1.0821x; 1.0147x over previous
//
#include <hip/hip_runtime.h>
#include <cstddef>

static constexpr int CB = 64;    // batch
static constexpr int CN = 512;   // nodes
static constexpr int CD = 256;   // node model dim
static constexpr int CE = 128;   // edge model dim
static constexpr int CIT = 20;   // sinkhorn iterations

typedef _Float16 half_t;
typedef __attribute__((ext_vector_type(8))) _Float16 v8h;
typedef __attribute__((ext_vector_type(4))) _Float16 v4h;
typedef __attribute__((ext_vector_type(4))) float v4f;

// ---------------------------------------------------------------------------
// k0: block 0 = mask layout detect; block 1 = idle; blocks 2..9 = W_a -> fp16
// B-fragments (w_aff folded); 10..17 = W_b; blocks >= 18 clear the dataflow
// slot region to -1.0f. flag: 0=int32, 1=uint8(bool), 2=float32, 3=int64
// ---------------------------------------------------------------------------
__global__ __launch_bounds__(512) void k0_init(
    const void* __restrict__ mask, int* __restrict__ flag,
    const float* __restrict__ W_a, const float* __restrict__ W_b,
    const float* __restrict__ w_aff,
    half_t* __restrict__ WaF, half_t* __restrict__ WbF,
    float4* __restrict__ clearp, int nclear4) {
  const int tid = threadIdx.x;
  const int blk = blockIdx.x;
  if (blk == 1) return;
  if (blk >= 18) {
    const int idx = (blk - 18) * 512 + tid;
    if (idx < nclear4)
      clearp[idx] = make_float4(-1.0f, -1.0f, -1.0f, -1.0f);
    return;
  }
  if (blk >= 2) {
    const bool is_a = (blk < 10);
    const float* W = is_a ? W_a : W_b;
    half_t* WF = is_a ? WaF : WbF;
    const int e = (blk - (is_a ? 2 : 10)) * 512 + tid;   // 0..4095
    const int fB = e >> 6, lane = e & 63;
    const int nn = fB >> 3, kf = fB & 7;
    const int col = nn * 16 + (lane & 15);
    const int q = lane >> 4;
    const float scale = is_a ? w_aff[col] : 1.0f;
    v8h hv;
#pragma unroll
    for (int j = 0; j < 8; ++j) {
      const int k = kf * 32 + q * 8 + j;
      hv[j] = (half_t)(W[(size_t)k * CE + col] * scale);
    }
    *(v8h*)&WF[(size_t)e * 8] = hv;
    return;
  }
  // blk == 0: mask dtype detection over first 32768 bytes
  __shared__ int cnt[5];
  if (tid < 5) cnt[tid] = 0;
  __syncthreads();
  const unsigned char* p = (const unsigned char*)mask;
  int l0 = 0, l1 = 0, l2 = 0, l3 = 0, l4 = 0;
  const int base = tid * 64;
  for (int k = 0; k < 64; ++k) {
    const int off = base + k;
    if (p[off]) {
      const int m4 = off & 3;
      if (m4 == 1) l1++;
      else if (m4 == 2) l2++;
      else if (m4 == 3) l3++;
      else if ((off & 7) == 4) l4++;
      else l0++;
    }
  }
  if (l0) atomicAdd(&cnt[0], 1);
  if (l1) atomicAdd(&cnt[1], 1);
  if (l2) atomicAdd(&cnt[2], 1);
  if (l3) atomicAdd(&cnt[3], 1);
  if (l4) atomicAdd(&cnt[4], 1);
  __syncthreads();
  if (tid == 0) {
    int f;
    if (cnt[1]) f = 1;
    else if (cnt[2] || cnt[3]) f = 2;
    else if (cnt[4]) f = 0;
    else if (cnt[0]) f = 3;
    else f = 1;
    *flag = f;
  }
}

// ---------------------------------------------------------------------------
// prep_both (validated R7/R8): ONE dispatch for both prep GEMMs. Blocks
// 0..511 = A-path (x = out_emb + pos, W = WaF w/ w_aff folded); 512..1023 =
// B-path (x = mask ? pad : in_emb, W = WbF). out fp16 row-major, K=256.
// ---------------------------------------------------------------------------
__global__ __launch_bounds__(256) void prep_both(
    const float* __restrict__ out_emb, const float* __restrict__ pos,
    const float* __restrict__ in_emb, const float* __restrict__ pad,
    const void* __restrict__ maskp, const int* __restrict__ flagp,
    const half_t* __restrict__ WaF, const half_t* __restrict__ WbF,
    half_t* __restrict__ A_h, half_t* __restrict__ Bm_h) {
  __shared__ half_t Xs[64][264];   // 33.8 KB
  const int tid = threadIdx.x;
  const int wv = tid >> 6, ln = tid & 63;
  const bool isA = blockIdx.x < 512;
  const int row0 = (isA ? blockIdx.x : blockIdx.x - 512) * 64;
  const float* X = isA ? out_emb : in_emb;
  const float* extra = isA ? pos : pad;
  const half_t* Wfrag = isA ? WaF : WbF;
  half_t* out = isA ? A_h : Bm_h;
  const int flag = isA ? 0 : *flagp;

#pragma unroll 4
  for (int it = 0; it < 16; ++it) {
    const int r = it * 4 + wv;
    const int row = row0 + r;
    const int c = ln * 4;
    float4 x4;
    if (isA) {
      x4 = *(const float4*)&X[(size_t)row * CD + c];
      const int i = row & (CN - 1);
      const float4 p4 = *(const float4*)&extra[(size_t)i * CD + c];
      x4.x += p4.x; x4.y += p4.y; x4.z += p4.z; x4.w += p4.w;
    } else {
      bool m;
      if (flag == 1)      m = ((const unsigned char*)maskp)[row] != 0;
      else if (flag == 2) m = ((const float*)maskp)[row] != 0.0f;
      else if (flag == 3) m = ((const long long*)maskp)[row] != 0;
      else                m = ((const int*)maskp)[row] != 0;
      if (m) x4 = *(const float4*)&extra[c];
      else   x4 = *(const float4*)&X[(size_t)row * CD + c];
    }
    v4h hv;
    hv[0] = (half_t)x4.x; hv[1] = (half_t)x4.y;
    hv[2] = (half_t)x4.z; hv[3] = (half_t)x4.w;
    *(v4h*)&Xs[r][c] = hv;
  }
  __syncthreads();

  const int q = ln >> 4, l = ln & 15;
  v8h af[8];
#pragma unroll
  for (int kf = 0; kf < 8; ++kf)
    af[kf] = *(v8h*)&Xs[wv * 16 + l][kf * 32 + q * 8];
  v4f acc[8] = {};
#pragma unroll
  for (int nn = 0; nn < 8; ++nn) {
    v8h bf[8];
#pragma unroll
    for (int kf = 0; kf < 8; ++kf)
      bf[kf] = *(const v8h*)&Wfrag[(size_t)((nn * 8 + kf) * 64 + ln) * 8];
#pragma unroll
    for (int kf = 0; kf < 8; ++kf)
      acc[nn] = __builtin_amdgcn_mfma_f32_16x16x32_f16(af[kf], bf[kf], acc[nn], 0, 0, 0);
  }
#pragma unroll
  for (int nn = 0; nn < 8; ++nn)
#pragma unroll
    for (int g = 0; g < 4; ++g) {
      const int row = row0 + wv * 16 + q * 4 + g;
      out[(size_t)row * CE + nn * 16 + l] = (half_t)acc[nn][g];
    }
}

// ---------------------------------------------------------------------------
// fused_reg: block = (batch b, 128-row slab), 512 thr = 8 waves, grid 256 =
// 1 block/CU, __launch_bounds__(512,2). E slab in registers TWICE as fp16:
//   eh[ct]  (C-layout = valid B-operand of mfma 16x16x16: row=k, col=n)
//   ehT[ct] (transposed twin from mfma(bf,af): holds E[row=lane&15][col=k])
// Sinkhorn passes are MFMAs:
//   pass1: P = sum_ct mfma(w_frag, ehT[ct], P)  -> p[row] replicated
//   pass2: s = mfma(u_frag, eh[ct], 0)          -> col partials, reduction
//          over the wave's 16 rows done by the matrix pipe (no swizzles)
// exp(aff + b_aff - ln16): 2^-4 scale cancels in both normalizations.
// Sync: barrier-free dataflow slots (pre-cleared -1, strictly-positive
// payload Q = 0.5*(ci*S1+S2), relaxed agent atomics — validated R5-R8).
// ---------------------------------------------------------------------------
__global__ __launch_bounds__(512, 2) void fused_reg(
    const half_t* __restrict__ A_h, const half_t* __restrict__ B_h,
    const float* __restrict__ baff, float* __restrict__ P,
    float* __restrict__ partInit, float* __restrict__ partIter) {
  __shared__ float comb2[8][512][2];     // 32 KB, [wave][col][s1|s2]
  __shared__ float2 w12[512];            // {0.5*v*csinv, v} fp32 (finalize)
  __shared__ float csinv_l[512];
  __shared__ half_t w1h[512];            // fp16 weights for pass1 fragments
  __shared__ half_t w2h[512];

  const int tid = threadIdx.x;
  const int wv = tid >> 6, ln = tid & 63;
  const int q = ln >> 4, l = ln & 15;
  const int b = blockIdx.x & 63;
  const int slab = blockIdx.x >> 6;
  const int i0 = slab * 128;
  const float bbs = *baff - 2.7725887f;   // fold 2^-4 scale into exp

  int rs3[3];   // the 3 remote slabs
  {
    int k = 0;
#pragma unroll
    for (int sl = 0; sl < 4; ++sl)
      if (sl != slab) rs3[k++] = sl;
  }

  // ---- GEMM: E and E^T tiles, fp16 MFMA, K=128 ----
  v8h af[4];
  {
    const half_t* Arow = &A_h[((size_t)b * CN + i0 + wv * 16 + l) * CE];
#pragma unroll
    for (int ki = 0; ki < 4; ++ki)
      af[ki] = *(const v8h*)&Arow[ki * 32 + q * 8];
  }
  v4h eh[32];    // E[row = wv*16 + q*4+g][col = ct*16 + l]
  v4h ehT[32];   // E[row = wv*16 + l][col = ct*16 + q*4+g]
  const half_t* Bbase = &B_h[(size_t)b * CN * CE];
#pragma unroll
  for (int ct = 0; ct < 32; ++ct) {
    v8h bf[4];
    const half_t* Brow = &Bbase[(size_t)(ct * 16 + l) * CE];
#pragma unroll
    for (int ki = 0; ki < 4; ++ki)
      bf[ki] = *(const v8h*)&Brow[ki * 32 + q * 8];
    v4f acc = {}, accT = {};
#pragma unroll
    for (int ki = 0; ki < 4; ++ki) {
      acc  = __builtin_amdgcn_mfma_f32_16x16x32_f16(af[ki], bf[ki], acc,  0, 0, 0);
      accT = __builtin_amdgcn_mfma_f32_16x16x32_f16(bf[ki], af[ki], accT, 0, 0, 0);
    }
#pragma unroll
    for (int g = 0; g < 4; ++g) {
      eh[ct][g]  = (half_t)__expf(acc[g]  + bbs);
      ehT[ct][g] = (half_t)__expf(accT[g] + bbs);
    }
  }

  // ---- init sums via MFMA (ones fragment) ----
  v4h ones;
  ones[0] = (half_t)1.0f; ones[1] = (half_t)1.0f;
  ones[2] = (half_t)1.0f; ones[3] = (half_t)1.0f;
  v4f rowacc = {};
#pragma unroll
  for (int ct = 0; ct < 32; ++ct) {
    const v4f c0 = __builtin_amdgcn_mfma_f32_16x16x16f16(ones, eh[ct], (v4f){}, 0, 0, 0);
    if (ln < 16) comb2[wv][ct * 16 + ln][0] = c0[0];   // colsum over 16 rows
    rowacc = __builtin_amdgcn_mfma_f32_16x16x16f16(ones, ehT[ct], rowacc, 0, 0, 0);
  }
  float rv[4];   // 1/rowsum for this lane's 4 rows (q*4+g)
#pragma unroll
  for (int g = 0; g < 4; ++g)
    rv[g] = 1.0f / __shfl(rowacc[0], q * 4 + g);
  __syncthreads();

  // ---- init exchange: column sums -> csinv; w init (v = 1) ----
  {
    float S = 0.0f;
#pragma unroll
    for (int w = 0; w < 8; ++w) S += comb2[w][tid][0];
    float T = S;
    __hip_atomic_store(&partInit[(((size_t)b * 4 + slab) * 512) + tid], S,
                       __ATOMIC_RELAXED, __HIP_MEMORY_SCOPE_AGENT);
    float v0, v1, v2;
    float* pb = &partInit[(size_t)b * 4 * 512];
    while (true) {
      v0 = __hip_atomic_load(&pb[rs3[0] * 512 + tid], __ATOMIC_RELAXED, __HIP_MEMORY_SCOPE_AGENT);
      v1 = __hip_atomic_load(&pb[rs3[1] * 512 + tid], __ATOMIC_RELAXED, __HIP_MEMORY_SCOPE_AGENT);
      v2 = __hip_atomic_load(&pb[rs3[2] * 512 + tid], __ATOMIC_RELAXED, __HIP_MEMORY_SCOPE_AGENT);
      if (v0 > 0.0f && v1 > 0.0f && v2 > 0.0f) break;
      __builtin_amdgcn_s_sleep(1);
    }
    T += v0 + v1 + v2;
    const float ci = 1.0f / T;
    csinv_l[tid] = ci;
    w12[tid] = make_float2(0.5f * ci, 1.0f);
    w1h[tid] = (half_t)(0.5f * ci);
    w2h[tid] = (half_t)1.0f;
  }

  // ---- 20 sinkhorn iterations (MFMA passes) ----
  float u_[4], uri[4];
  for (int t = 0; t < CIT; ++t) {
    __syncthreads();   // w1h/w2h ready
    // pass 1: row dots via E^T tiles; weight fragments from LDS (broadcast)
    v4f P1 = {}, P2 = {};
#pragma unroll
    for (int ct = 0; ct < 32; ++ct) {
      const v4h w1f = *(const v4h*)&w1h[ct * 16 + q * 4];
      const v4h w2f = *(const v4h*)&w2h[ct * 16 + q * 4];
      P1 = __builtin_amdgcn_mfma_f32_16x16x16f16(w1f, ehT[ct], P1, 0, 0, 0);
      P2 = __builtin_amdgcn_mfma_f32_16x16x16f16(w2f, ehT[ct], P2, 0, 0, 0);
    }
    // redistribute p[row l&15] -> this lane's rows q*4+g; compute u
    v4h u_h, uri_h;
#pragma unroll
    for (int g = 0; g < 4; ++g) {
      const float p1 = __shfl(P1[0], q * 4 + g);
      const float p2 = __shfl(P2[0], q * 4 + g);
      u_[g] = 1.0f / (p1 + 0.5f * rv[g] * p2);
      uri[g] = u_[g] * rv[g];
      u_h[g] = (half_t)u_[g];
      uri_h[g] = (half_t)uri[g];
    }
    // pass 2: column partials via E tiles; 16-row reduce inside the MFMA
#pragma unroll
    for (int ct = 0; ct < 32; ++ct) {
      const v4f sA = __builtin_amdgcn_mfma_f32_16x16x16f16(u_h,   eh[ct], (v4f){}, 0, 0, 0);
      const v4f sB = __builtin_amdgcn_mfma_f32_16x16x16f16(uri_h, eh[ct], (v4f){}, 0, 0, 0);
      if (ln < 32) comb2[wv][ct * 16 + (ln & 15)][ln >> 4] = (ln < 16) ? sA[0] : sB[0];
    }
    __syncthreads();
    // cross-wave reduce + pre-combined publish: Q = 0.5*(ci*S1 + S2)
    float S1 = 0.0f, S2 = 0.0f;
#pragma unroll
    for (int w = 0; w < 8; ++w) {
      const float2 c2 = *(const float2*)&comb2[w][tid][0];
      S1 += c2.x;
      S2 += c2.y;
    }
    const float ci = csinv_l[tid];
    const float Q = 0.5f * fmaf(ci, S1, S2);
    float* pr = &partIter[(((size_t)t * 64 + b) * 4) * 512];
    __hip_atomic_store(&pr[slab * 512 + tid], Q,
                       __ATOMIC_RELAXED, __HIP_MEMORY_SCOPE_AGENT);
    float v0, v1, v2;
    while (true) {
      v0 = __hip_atomic_load(&pr[rs3[0] * 512 + tid], __ATOMIC_RELAXED, __HIP_MEMORY_SCOPE_AGENT);
      v1 = __hip_atomic_load(&pr[rs3[1] * 512 + tid], __ATOMIC_RELAXED, __HIP_MEMORY_SCOPE_AGENT);
      v2 = __hip_atomic_load(&pr[rs3[2] * 512 + tid], __ATOMIC_RELAXED, __HIP_MEMORY_SCOPE_AGENT);
      if (v0 > 0.0f && v1 > 0.0f && v2 > 0.0f) break;
      __builtin_amdgcn_s_sleep(1);
    }
    const float vv = 1.0f / (Q + v0 + v1 + v2);
    w12[tid] = make_float2(0.5f * vv * ci, vv);
    w1h[tid] = (half_t)(0.5f * vv * ci);
    w2h[tid] = (half_t)vv;
  }

  // ---- finalize: P = E * u_i * v_j * (0.5*csinv_j + 0.5*rinv_i) ----
  __syncthreads();
  float* Pb = &P[((size_t)b * CN + i0 + wv * 16 + q * 4) * CN];
#pragma unroll
  for (int ct = 0; ct < 32; ++ct) {
    const float2 w = w12[ct * 16 + l];
    const float c1 = w.x;
    const float c2 = 0.5f * w.y;
#pragma unroll
    for (int g = 0; g < 4; ++g) {
      const float e = (float)eh[ct][g];
      Pb[(size_t)g * CN + ct * 16 + l] = e * fmaf(u_[g], c1, uri[g] * c2);
    }
  }
}

// ---------------------------------------------------------------------------
extern "C" void kernel_launch(void* const* d_in, const int* in_sizes, int n_in,
                              void* d_out, int out_size, void* d_ws, size_t ws_size,
                              hipStream_t stream) {
  const float* in_emb  = (const float*)d_in[0];
  const void*  mask    = d_in[1];
  const float* out_emb = (const float*)d_in[2];
  const float* pad     = (const float*)d_in[3];
  const float* pos     = (const float*)d_in[4];
  const float* W_a     = (const float*)d_in[5];
  const float* W_b     = (const float*)d_in[6];
  const float* w_aff   = (const float*)d_in[7];
  const float* b_aff   = (const float*)d_in[8];
  float* P = (float*)d_out;

  char* ws = (char*)d_ws;
  const size_t MB = 1024 * 1024;
  half_t* A_h  = (half_t*)ws;                              // 8 MB
  half_t* Bm_h = (half_t*)(ws + 8 * MB);                   // 8 MB
  int*    flag = (int*)(ws + 16 * MB);                     // 4 B
  half_t* WaF  = (half_t*)(ws + 16 * MB + 16384);          // 64 KB
  half_t* WbF  = (half_t*)(ws + 16 * MB + 16384 + 65536);  // 64 KB
  float* partInit = (float*)(ws + 16 * MB + 256 * 1024);   // 512 KB
  float* partIter = (float*)(ws + 16 * MB + 768 * 1024);   // 10 MB

  // dataflow slots: 10.5 MB contiguous starting at partInit
  const int nclear4 = (512 * 1024 + 10 * 1024 * 1024) / 16;   // 688,128 float4
  const int nclrblk = (nclear4 + 511) / 512;                  // 1344

  k0_init<<<dim3(18 + nclrblk), dim3(512), 0, stream>>>(
      mask, flag, W_a, W_b, w_aff, WaF, WbF, (float4*)partInit, nclear4);
  prep_both<<<dim3(1024), dim3(256), 0, stream>>>(
      out_emb, pos, in_emb, pad, mask, flag, WaF, WbF, A_h, Bm_h);
  fused_reg<<<dim3(256), dim3(512), 0, stream>>>(
      A_h, Bm_h, b_aff, P, partInit, partIter);
}